// Round 1
// baseline (115.956 us; speedup 1.0000x reference)
//
#include <hip/hip_runtime.h>

// The reference's output is identically zero:
//   m = max(y, axis=1, keepdims=True)            -> (B, 1)
//   centered = m - mean(m, axis=1, keepdims=True) = m - m = 0.0 (exact, finite inputs)
//   gelu_tanh(0) = 0.0 (exact)
// So kernel_launch only needs to overwrite the 0xAA-poisoned d_out with zeros.

__global__ void ModelNew_25056839205334_zero(float4* __restrict__ out, int n4) {
    int i = blockIdx.x * blockDim.x + threadIdx.x;
    // grid-stride for safety; n4 = out_size/4 vec4 stores
    for (; i < n4; i += gridDim.x * blockDim.x) {
        out[i] = make_float4(0.0f, 0.0f, 0.0f, 0.0f);
    }
}

__global__ void ModelNew_25056839205334_zero_tail(float* __restrict__ out, int start, int n) {
    int i = start + blockIdx.x * blockDim.x + threadIdx.x;
    if (i < n) out[i] = 0.0f;
}

extern "C" void kernel_launch(void* const* d_in, const int* in_sizes, int n_in,
                              void* d_out, int out_size, void* d_ws, size_t ws_size,
                              hipStream_t stream) {
    (void)d_in; (void)in_sizes; (void)n_in; (void)d_ws; (void)ws_size;

    float* out = (float*)d_out;
    int n4 = out_size / 4;          // out_size = 4096 -> 1024 float4 stores
    int tail = out_size - n4 * 4;   // 0 for this problem

    if (n4 > 0) {
        int threads = 256;
        int blocks = (n4 + threads - 1) / threads;  // 4 blocks
        if (blocks > 1024) blocks = 1024;
        ModelNew_25056839205334_zero<<<blocks, threads, 0, stream>>>((float4*)out, n4);
    }
    if (tail > 0) {
        ModelNew_25056839205334_zero_tail<<<1, 64, 0, stream>>>(out, n4 * 4, out_size);
    }
}